// Round 9
// baseline (833.858 us; speedup 1.0000x reference)
//
#include <hip/hip_runtime.h>
#include <hip/hip_bf16.h>

#define BATCH   16
#define N_ANC   8649      // 31*31*9
#define SORT_N  16384     // padded pow2
#define PRE     6000
#define POST    1500
#define RWORDS  192       // padded mask row stride in words (768 B, 48 uint4)
#define MROWS   6016      // rows incl. 16 pad rows (group 187)
#define NGRP    188       // 188 groups of 32 rows

// ---------------- Kernel 1: decode boxes + build sort keys ----------------
__global__ __launch_bounds__(256) void k_decode(
    const float* __restrict__ deltas, const float* __restrict__ probs,
    const float* __restrict__ anchors, float4* __restrict__ boxes,
    unsigned long long* __restrict__ keys)
{
    int t = blockIdx.x * 256 + threadIdx.x;
    if (t >= BATCH * SORT_N) return;
    int b = t / SORT_N;
    int n = t - b * SORT_N;
    if (n >= N_ANC) { keys[t] = ~0ULL; return; }

    float s = probs[(size_t)b * N_ANC + n];
    unsigned int bits = __float_as_uint(s);
    unsigned int u = bits ^ ((bits & 0x80000000u) ? 0xFFFFFFFFu : 0x80000000u);
    keys[(size_t)b * SORT_N + n] = ((unsigned long long)(~u) << 32) | (unsigned int)n;

    float4 a = ((const float4*)anchors)[n];
    float4 d = ((const float4*)deltas)[(size_t)b * N_ANC + n];
    float dy = d.x * 0.1f, dx = d.y * 0.1f, dh = d.z * 0.2f, dw = d.w * 0.2f;
    float ah = a.z - a.x, aw = a.w - a.y;
    float cy = a.x + 0.5f * ah, cx = a.y + 0.5f * aw;
    float bh = expf(dh) * ah, bw = expf(dw) * aw;
    float bcy = dy * ah + cy, bcx = dx * aw + cx;
    float y1 = bcy - 0.5f * bh, x1 = bcx - 0.5f * bw;
    boxes[(size_t)b * N_ANC + n] = make_float4(y1, x1, y1 + bh, x1 + bw);
}

// ---------------- Kernel 2a: per-chunk bitonic sort (2 blocks / batch) ----------------
__global__ __launch_bounds__(1024) void k_sort_chunk(unsigned long long* __restrict__ keys)
{
    __shared__ unsigned long long sb[8192];   // 64 KB
    int b = blockIdx.x >> 1;
    int c = blockIdx.x & 1;
    unsigned long long* g = keys + (size_t)b * SORT_N + c * 8192;

    for (int t = threadIdx.x; t < 8192; t += 1024) sb[t] = g[t];
    __syncthreads();
    for (int k = 2; k <= 8192; k <<= 1) {
        for (int j = k >> 1; j >= 1; j >>= 1) {
            for (int p = threadIdx.x; p < 4096; p += 1024) {
                int i  = ((p & ~(j - 1)) << 1) | (p & (j - 1));
                int gi = (c << 13) | i;
                bool asc = ((gi & k) == 0);
                unsigned long long a = sb[i], b2 = sb[i | j];
                bool sw = asc ? (a > b2) : (a < b2);
                if (sw) { sb[i] = b2; sb[i | j] = a; }
            }
            __syncthreads();
        }
    }
    for (int t = threadIdx.x; t < 8192; t += 1024) g[t] = sb[t];
}

// ---------------- Kernel 2b: merge (1 block / batch), keep top 6016 ----------------
__global__ __launch_bounds__(1024) void k_sort_merge(unsigned long long* __restrict__ keys)
{
    __shared__ unsigned long long sb[8192];   // 64 KB
    int b = blockIdx.x;
    unsigned long long* kb = keys + (size_t)b * SORT_N;

    for (int p = threadIdx.x; p < 8192; p += 1024) {
        unsigned long long a = kb[p], b2 = kb[p + 8192];
        if (a > b2) { kb[p] = b2; kb[p + 8192] = a; }
    }
    __syncthreads();

    for (int t = threadIdx.x; t < 8192; t += 1024) sb[t] = kb[t];
    __syncthreads();
    for (int j = 4096; j >= 1; j >>= 1) {
        for (int p = threadIdx.x; p < 4096; p += 1024) {
            int i = ((p & ~(j - 1)) << 1) | (p & (j - 1));
            unsigned long long a = sb[i], b2 = sb[i | j];
            if (a > b2) { sb[i] = b2; sb[i | j] = a; }
        }
        __syncthreads();
    }
    for (int t = threadIdx.x; t < 6016; t += 1024) kb[t] = sb[t];
}

// ---------------- Kernel 3: gather sorted boxes/scores ----------------
__global__ __launch_bounds__(256) void k_gather(
    const unsigned long long* __restrict__ keys, const float4* __restrict__ boxes,
    const float* __restrict__ probs,
    float4* __restrict__ sboxes, float* __restrict__ sscores)
{
    int t = blockIdx.x * 256 + threadIdx.x;
    if (t >= BATCH * PRE) return;
    int b = t / PRE;
    int r = t - b * PRE;
    unsigned long long k = keys[(size_t)b * SORT_N + r];
    int idx = (int)(k & 0xFFFFFFFFu);
    sboxes[(size_t)b * PRE + r]  = boxes[(size_t)b * N_ANC + idx];
    sscores[(size_t)b * PRE + r] = probs[(size_t)b * N_ANC + idx];
}

// ---------------- Kernel 4: IoU bit-matrix, 1024-row x 256-col tiles, 4 rows/thread ----
// Amortizes LDS j-box reads over 4 i-rows (20B -> 5B per pair).
__global__ __launch_bounds__(256) void k_iou(
    const float4* __restrict__ sboxes, unsigned int* __restrict__ mask,
    unsigned int* __restrict__ diag)
{
    int it = blockIdx.x;          // i-tile: rows it*1024 .. +1023
    int jt = blockIdx.y;          // j-tile: cols jt*256 .. +255
    int b  = blockIdx.z;
    int ibase = it * 1024;
    int jbase0 = jt * 256;
    if (jbase0 + 255 <= ibase) return;   // no j > i in this tile

    __shared__ float4 jb[256];
    __shared__ float  ja[256];
    int t = threadIdx.x;
    int j = jbase0 + t;
    float4 bj = (j < PRE) ? sboxes[(size_t)b * PRE + j]
                          : make_float4(-2e6f, -2e6f, -1.5e6f, -1.5e6f); // far dummy, area>0
    jb[t] = bj;
    ja[t] = (bj.z - bj.x) * (bj.w - bj.y);
    __syncthreads();

    float4 bi[4];
    float  ai[4];
    int    ir[4];
    #pragma unroll
    for (int r = 0; r < 4; r++) {
        ir[r] = ibase + t + 256 * r;
        bi[r] = (ir[r] < PRE) ? sboxes[(size_t)b * PRE + ir[r]]
                              : make_float4(0.f, 0.f, 0.f, 0.f);
        ai[r] = (bi[r].z - bi[r].x) * (bi[r].w - bi[r].y);
    }

    unsigned int w[4][8];
    for (int wq = 0; wq < 8; wq++) {
        int jbase = jbase0 + wq * 32;
        unsigned int bits0 = 0, bits1 = 0, bits2 = 0, bits3 = 0;
        #pragma unroll
        for (int jj = 0; jj < 32; jj++) {
            int lj = wq * 32 + jj;
            float4 bx = jb[lj];
            float  aj = ja[lj];
            int    jg = jbase + jj;
            #pragma unroll
            for (int r = 0; r < 4; r++) {
                float ih = fmaxf(fminf(bi[r].z, bx.z) - fmaxf(bi[r].x, bx.x), 0.0f);
                float iw = fmaxf(fminf(bi[r].w, bx.w) - fmaxf(bi[r].y, bx.y), 0.0f);
                float inter = ih * iw;
                float iou = inter / (ai[r] + aj - inter + 1e-8f);
                bool set = (iou > 0.7f) && (jg > ir[r]);
                unsigned int bit = set ? (1u << jj) : 0u;
                if (r == 0) bits0 |= bit;
                else if (r == 1) bits1 |= bit;
                else if (r == 2) bits2 |= bit;
                else bits3 |= bit;
            }
        }
        w[0][wq] = bits0; w[1][wq] = bits1; w[2][wq] = bits2; w[3][wq] = bits3;
    }

    #pragma unroll
    for (int r = 0; r < 4; r++) {
        if (ir[r] < PRE) {
            unsigned int* row = mask + ((size_t)b * MROWS + ir[r]) * RWORDS + jt * 8;
            ((uint4*)row)[0] = make_uint4(w[r][0], w[r][1], w[r][2], w[r][3]);
            ((uint4*)row)[1] = make_uint4(w[r][4], w[r][5], w[r][6], w[r][7]);
            if ((ir[r] >> 8) == jt)
                diag[(size_t)b * MROWS + ir[r]] = w[r][(ir[r] >> 5) & 7];
        }
    }
}

// ---------------- Kernel 5: fully-pipelined group-32 scan (1 wave / batch) ----------
// ALL load addresses are static; only the masked-OR uses are data-dependent.
// Unconditional loads (sub-diagonal garbage ORs only into already-consumed state
// words - harmless) + manual 2-group double buffer under launch_bounds(64,1).
#define PROCESS_GROUP(G, R, T)                                                   \
    do {                                                                         \
        unsigned int cw_ = ((G) & 2) ? (((G) & 1) ? st.w : st.z)                 \
                                     : (((G) & 1) ? st.y : st.x);                \
        unsigned int swv_ = __shfl(cw_, (G) >> 2);                               \
        unsigned int tri_[32];                                                   \
        _Pragma("unroll")                                                        \
        for (int q_ = 0; q_ < 8; q_++) {                                         \
            tri_[4*q_]   = T[q_].x; tri_[4*q_+1] = T[q_].y;                      \
            tri_[4*q_+2] = T[q_].z; tri_[4*q_+3] = T[q_].w;                      \
        }                                                                        \
        unsigned int valid_ = ((G) == NGRP - 1) ? 0xFFFFu : 0xFFFFFFFFu;         \
        unsigned int alive_ = ~swv_ & valid_;                                    \
        unsigned int keepm_ = 0;                                                 \
        _Pragma("unroll")                                                        \
        for (int k_ = 0; k_ < 32; k_++) {                                        \
            unsigned int bit_ = (alive_ >> k_) & 1u;                             \
            keepm_ |= bit_ << k_;                                                \
            alive_ &= ~((0u - bit_) & tri_[k_]);                                 \
        }                                                                        \
        int need_ = POST - cnt;                                                  \
        int rank_ = __popc(keepm_ & below);                                      \
        bool kme_ = (lane < 32) && (keepm_ & lbit) && (rank_ < need_);           \
        unsigned long long bal_ = __ballot(kme_);                                \
        unsigned int km2_ = (unsigned int)bal_;                                  \
        if (kme_) oi[cnt + rank_] = (G) * 32 + lane;                             \
        _Pragma("unroll")                                                        \
        for (int k_ = 0; k_ < 32; k_++) {                                        \
            unsigned int m_ = 0u - ((km2_ >> k_) & 1u);                          \
            st.x |= R[k_].x & m_; st.y |= R[k_].y & m_;                          \
            st.z |= R[k_].z & m_; st.w |= R[k_].w & m_;                          \
        }                                                                        \
        cnt += __popc(km2_);                                                     \
    } while (0)

__global__ __launch_bounds__(64, 1) void k_scan(
    const unsigned int* __restrict__ mask, const unsigned int* __restrict__ diag,
    int* __restrict__ out_idx, int* __restrict__ out_cnt)
{
    int b = blockIdx.x;
    int lane = threadIdx.x;
    const uint4* m4 = (const uint4*)(mask + (size_t)b * MROWS * RWORDS); // 48 quads/row
    const unsigned int* db = diag + (size_t)b * MROWS;
    unsigned int lbit  = 1u << (lane & 31);
    unsigned int below = lbit - 1u;

    uint4 st = make_uint4(0, 0, 0, 0);
    int cnt = 0;
    int* oi = out_idx + b * POST;

    uint4 rA[32], rB[32];
    uint4 tA[8],  tB[8];

    #pragma unroll
    for (int k = 0; k < 32; k++) rA[k] = m4[(size_t)k * 48 + lane];
    #pragma unroll
    for (int q = 0; q < 8; q++) tA[q] = ((const uint4*)db)[q];

    for (int g = 0; g < NGRP; g += 2) {
        // issue loads for group g+1 (always valid: NGRP even)
        #pragma unroll
        for (int k = 0; k < 32; k++)
            rB[k] = m4[(size_t)((g + 1) * 32 + k) * 48 + lane];
        #pragma unroll
        for (int q = 0; q < 8; q++)
            tB[q] = ((const uint4*)(db + (g + 1) * 32))[q];

        PROCESS_GROUP(g, rA, tA);

        if (g + 2 < NGRP) {
            #pragma unroll
            for (int k = 0; k < 32; k++)
                rA[k] = m4[(size_t)((g + 2) * 32 + k) * 48 + lane];
            #pragma unroll
            for (int q = 0; q < 8; q++)
                tA[q] = ((const uint4*)(db + (g + 2) * 32))[q];
        }

        PROCESS_GROUP(g + 1, rB, tB);
    }
    if (lane == 0) out_cnt[b] = cnt;
}

// ---------------- Kernel 6: compact + clip output ----------------
__global__ __launch_bounds__(256) void k_out(
    const float4* __restrict__ sboxes, const float* __restrict__ sscores,
    const int* __restrict__ out_idx, const int* __restrict__ out_cnt,
    float* __restrict__ out)
{
    int t = blockIdx.x * 256 + threadIdx.x;
    if (t >= BATCH * POST) return;
    int b = t / POST;
    int r = t - b * POST;
    float4 v = make_float4(0, 0, 0, 0);
    float sc = 0.f;
    if (r < out_cnt[b]) {
        int i = out_idx[b * POST + r];
        float4 bx = sboxes[(size_t)b * PRE + i];
        v.x = fminf(fmaxf(bx.x, 0.f), 1.f);
        v.y = fminf(fmaxf(bx.y, 0.f), 1.f);
        v.z = fminf(fmaxf(bx.z, 0.f), 1.f);
        v.w = fminf(fmaxf(bx.w, 0.f), 1.f);
        sc = sscores[(size_t)b * PRE + i];
    }
    ((float4*)out)[t] = v;                  // roi_bboxes
    out[(size_t)BATCH * POST * 4 + t] = sc; // roi_scores
}

// ---------------- host ----------------
extern "C" void kernel_launch(void* const* d_in, const int* in_sizes, int n_in,
                              void* d_out, int out_size, void* d_ws, size_t ws_size,
                              hipStream_t stream)
{
    const float* deltas  = (const float*)d_in[0];
    const float* probs   = (const float*)d_in[1];
    const float* anchors = (const float*)d_in[2];
    float* out = (float*)d_out;

    char* ws = (char*)d_ws;
    size_t off = 0;
    auto alloc = [&](size_t bytes) {
        size_t o = off;
        off = (off + bytes + 255) & ~(size_t)255;
        return o;
    };
    float4* boxes            = (float4*)(ws + alloc((size_t)BATCH * N_ANC * 16));
    unsigned long long* keys = (unsigned long long*)(ws + alloc((size_t)BATCH * SORT_N * 8));
    float4* sboxes           = (float4*)(ws + alloc((size_t)BATCH * PRE * 16));
    float* sscores           = (float*)(ws + alloc((size_t)BATCH * PRE * 4));
    unsigned int* mask       = (unsigned int*)(ws + alloc((size_t)BATCH * MROWS * RWORDS * 4));
    unsigned int* diag       = (unsigned int*)(ws + alloc((size_t)BATCH * MROWS * 4));
    int* oidx                = (int*)(ws + alloc((size_t)BATCH * POST * 4));
    int* ocnt                = (int*)(ws + alloc((size_t)BATCH * 4));

    k_decode<<<(BATCH * SORT_N + 255) / 256, 256, 0, stream>>>(deltas, probs, anchors, boxes, keys);
    k_sort_chunk<<<BATCH * 2, 1024, 0, stream>>>(keys);
    k_sort_merge<<<BATCH, 1024, 0, stream>>>(keys);
    k_gather<<<(BATCH * PRE + 255) / 256, 256, 0, stream>>>(keys, boxes, probs, sboxes, sscores);
    k_iou<<<dim3(6, 24, BATCH), 256, 0, stream>>>(sboxes, mask, diag);
    k_scan<<<BATCH, 64, 0, stream>>>(mask, diag, oidx, ocnt);
    k_out<<<(BATCH * POST + 255) / 256, 256, 0, stream>>>(sboxes, sscores, oidx, ocnt, out);
}

// Round 10
// 694.339 us; speedup vs baseline: 1.2009x; 1.2009x over previous
//
#include <hip/hip_runtime.h>
#include <hip/hip_bf16.h>

#define BATCH   16
#define N_ANC   8649      // 31*31*9
#define SORT_N  16384     // padded pow2
#define PRE     6000
#define POST    1500
#define ROWW    188       // u32 words per mask row (752 B, 47 uint4)
#define MROWS   6016      // rows incl. 16 pad rows (group 187)
#define NGRP    188       // 188 groups of 32 rows
#define GQUADS  1504      // quads per 32-row group (32*47)
#define TI      256
#define TJ      256

// ---------------- Kernel 1: decode boxes + build sort keys ----------------
__global__ __launch_bounds__(256) void k_decode(
    const float* __restrict__ deltas, const float* __restrict__ probs,
    const float* __restrict__ anchors, float4* __restrict__ boxes,
    unsigned long long* __restrict__ keys)
{
    int t = blockIdx.x * 256 + threadIdx.x;
    if (t >= BATCH * SORT_N) return;
    int b = t / SORT_N;
    int n = t - b * SORT_N;
    if (n >= N_ANC) { keys[t] = ~0ULL; return; }

    float s = probs[(size_t)b * N_ANC + n];
    unsigned int bits = __float_as_uint(s);
    unsigned int u = bits ^ ((bits & 0x80000000u) ? 0xFFFFFFFFu : 0x80000000u);
    keys[(size_t)b * SORT_N + n] = ((unsigned long long)(~u) << 32) | (unsigned int)n;

    float4 a = ((const float4*)anchors)[n];
    float4 d = ((const float4*)deltas)[(size_t)b * N_ANC + n];
    float dy = d.x * 0.1f, dx = d.y * 0.1f, dh = d.z * 0.2f, dw = d.w * 0.2f;
    float ah = a.z - a.x, aw = a.w - a.y;
    float cy = a.x + 0.5f * ah, cx = a.y + 0.5f * aw;
    float bh = expf(dh) * ah, bw = expf(dw) * aw;
    float bcy = dy * ah + cy, bcx = dx * aw + cx;
    float y1 = bcy - 0.5f * bh, x1 = bcx - 0.5f * bw;
    boxes[(size_t)b * N_ANC + n] = make_float4(y1, x1, y1 + bh, x1 + bw);
}

// ---------------- Kernel 2a: per-chunk bitonic sort (2 blocks / batch) ----------------
__global__ __launch_bounds__(1024) void k_sort_chunk(unsigned long long* __restrict__ keys)
{
    __shared__ unsigned long long sb[8192];   // 64 KB
    int b = blockIdx.x >> 1;
    int c = blockIdx.x & 1;
    unsigned long long* g = keys + (size_t)b * SORT_N + c * 8192;

    for (int t = threadIdx.x; t < 8192; t += 1024) sb[t] = g[t];
    __syncthreads();
    for (int k = 2; k <= 8192; k <<= 1) {
        for (int j = k >> 1; j >= 1; j >>= 1) {
            for (int p = threadIdx.x; p < 4096; p += 1024) {
                int i  = ((p & ~(j - 1)) << 1) | (p & (j - 1));
                int gi = (c << 13) | i;
                bool asc = ((gi & k) == 0);
                unsigned long long a = sb[i], b2 = sb[i | j];
                bool sw = asc ? (a > b2) : (a < b2);
                if (sw) { sb[i] = b2; sb[i | j] = a; }
            }
            __syncthreads();
        }
    }
    for (int t = threadIdx.x; t < 8192; t += 1024) g[t] = sb[t];
}

// ---------------- Kernel 2b: merge (1 block / batch), keep top 6016 ----------------
__global__ __launch_bounds__(1024) void k_sort_merge(unsigned long long* __restrict__ keys)
{
    __shared__ unsigned long long sb[8192];   // 64 KB
    int b = blockIdx.x;
    unsigned long long* kb = keys + (size_t)b * SORT_N;

    for (int p = threadIdx.x; p < 8192; p += 1024) {
        unsigned long long a = kb[p], b2 = kb[p + 8192];
        if (a > b2) { kb[p] = b2; kb[p + 8192] = a; }
    }
    __syncthreads();

    for (int t = threadIdx.x; t < 8192; t += 1024) sb[t] = kb[t];
    __syncthreads();
    for (int j = 4096; j >= 1; j >>= 1) {
        for (int p = threadIdx.x; p < 4096; p += 1024) {
            int i = ((p & ~(j - 1)) << 1) | (p & (j - 1));
            unsigned long long a = sb[i], b2 = sb[i | j];
            if (a > b2) { sb[i] = b2; sb[i | j] = a; }
        }
        __syncthreads();
    }
    for (int t = threadIdx.x; t < 6016; t += 1024) kb[t] = sb[t];
}

// ---------------- Kernel 3: gather sorted boxes/scores ----------------
__global__ __launch_bounds__(256) void k_gather(
    const unsigned long long* __restrict__ keys, const float4* __restrict__ boxes,
    const float* __restrict__ probs,
    float4* __restrict__ sboxes, float* __restrict__ sscores)
{
    int t = blockIdx.x * 256 + threadIdx.x;
    if (t >= BATCH * PRE) return;
    int b = t / PRE;
    int r = t - b * PRE;
    unsigned long long k = keys[(size_t)b * SORT_N + r];
    int idx = (int)(k & 0xFFFFFFFFu);
    sboxes[(size_t)b * PRE + r]  = boxes[(size_t)b * N_ANC + idx];
    sscores[(size_t)b * PRE + r] = probs[(size_t)b * N_ANC + idx];
}

// ---------------- Kernel 4: IoU bit-matrix, 256x256 tiles, upper triangle ----------------
// (round-5 structure: best measured 304 us, VALUBusy 82%)
__global__ __launch_bounds__(256) void k_iou(
    const float4* __restrict__ sboxes, unsigned int* __restrict__ mask)
{
    int it = blockIdx.x;   // row tile 0..23
    int jt = blockIdx.y;   // col tile 0..23
    int b  = blockIdx.z;
    if (jt < it) return;   // lower-triangle tiles never consumed by scan

    __shared__ float4 jb[TJ];
    __shared__ float  ja[TJ];
    int t = threadIdx.x;
    int j = jt * TJ + t;
    float4 bj = (j < PRE) ? sboxes[(size_t)b * PRE + j]
                          : make_float4(-2e6f, -2e6f, -1.5e6f, -1.5e6f); // far dummy, area>0
    jb[t] = bj;
    ja[t] = (bj.z - bj.x) * (bj.w - bj.y);
    __syncthreads();

    int i = it * TI + t;
    if (i >= PRE) return;
    float4 bi = sboxes[(size_t)b * PRE + i];
    float areai = (bi.z - bi.x) * (bi.w - bi.y);

    unsigned int w[8];
    if (jt > it) {
        for (int wq = 0; wq < 8; wq++) {
            unsigned int bits = 0u;
            #pragma unroll
            for (int jj = 0; jj < 32; jj++) {
                int lj = wq * 32 + jj;
                float4 bx = jb[lj];
                float ih = fmaxf(fminf(bi.z, bx.z) - fmaxf(bi.x, bx.x), 0.0f);
                float iw = fmaxf(fminf(bi.w, bx.w) - fmaxf(bi.y, bx.y), 0.0f);
                float inter = ih * iw;
                float iou = inter / (areai + ja[lj] - inter + 1e-8f);
                if (iou > 0.7f) bits |= (1u << jj);
            }
            w[wq] = bits;
        }
    } else {
        for (int wq = 0; wq < 8; wq++) {
            int jbase = jt * TJ + wq * 32;
            unsigned int bits = 0u;
            if (jbase + 31 > i) {
                #pragma unroll
                for (int jj = 0; jj < 32; jj++) {
                    int lj = wq * 32 + jj;
                    float4 bx = jb[lj];
                    float ih = fmaxf(fminf(bi.z, bx.z) - fmaxf(bi.x, bx.x), 0.0f);
                    float iw = fmaxf(fminf(bi.w, bx.w) - fmaxf(bi.y, bx.y), 0.0f);
                    float inter = ih * iw;
                    float iou = inter / (areai + ja[lj] - inter + 1e-8f);
                    if (iou > 0.7f && (jbase + jj) > i) bits |= (1u << jj);
                }
            }
            w[wq] = bits;
        }
    }

    unsigned int* row = mask + ((size_t)b * MROWS + i) * ROWW + jt * 8;
    ((uint4*)row)[0] = make_uint4(w[0], w[1], w[2], w[3]);
    if (jt < 23) ((uint4*)row)[1] = make_uint4(w[4], w[5], w[6], w[7]);
}

// ---------------- Kernel 5: 4-wave producer/consumer group scan (1 block / batch) ----
// Thread t owns state word t (1 VGPR). Group rows (24 KB, contiguous) double-
// buffered in LDS via reg-staging by all 4 waves. The group's decision word is
// published by its owner thread into a parity slot during the PREVIOUS group's
// OR phase -> exactly one barrier per group. Resolve replicated in all threads
// from broadcast LDS reads; cap fused into the chain (exact reference semantics).
__global__ __launch_bounds__(256, 1) void k_scan(
    const unsigned int* __restrict__ mask,
    int* __restrict__ out_idx, int* __restrict__ out_cnt)
{
    __shared__ unsigned int rows[2][32 * ROWW];   // 2 x 24064 B
    __shared__ unsigned int sw_lds[2];
    int b   = blockIdx.x;
    int tid = threadIdx.x;
    const uint4* mb = (const uint4*)(mask + (size_t)b * MROWS * ROWW);

    if (tid < 2) sw_lds[tid] = 0u;

    // prologue: stage group 0
    uint4 sreg[6];
    #pragma unroll
    for (int i = 0; i < 6; i++) {
        int q = tid + i * 256;
        sreg[i] = (q < GQUADS) ? mb[q] : make_uint4(0, 0, 0, 0);
    }
    #pragma unroll
    for (int i = 0; i < 6; i++) {
        int q = tid + i * 256;
        if (q < GQUADS) ((uint4*)rows[0])[q] = sreg[i];
    }
    __syncthreads();

    unsigned int st_word = 0u;    // this thread's owned state word (tid < ROWW)
    int cnt = 0;
    int* oi = out_idx + b * POST;

    for (int g = 0; g < NGRP; g++) {
        int cur = g & 1;
        bool have_next = (g + 1 < NGRP);

        // A: issue next-group global loads into regs (latency hides under resolve)
        if (have_next) {
            const uint4* src = mb + (size_t)(g + 1) * GQUADS;
            #pragma unroll
            for (int i = 0; i < 6; i++) {
                int q = tid + i * 256;
                sreg[i] = (q < GQUADS) ? src[q] : make_uint4(0, 0, 0, 0);
            }
        }

        // B: intra-group diagonal words (broadcast LDS reads, replicated)
        unsigned int tri[32];
        #pragma unroll
        for (int k = 0; k < 32; k++) tri[k] = rows[cur][k * ROWW + g];

        // C: this group's state word (published during previous group)
        unsigned int sw = sw_lds[cur];

        // D: serial resolve with fused cap (identical in all threads)
        int need_n = POST - cnt;
        unsigned int valid = (g == NGRP - 1) ? 0xFFFFu : 0xFFFFFFFFu;
        unsigned int alive = ~sw & valid;
        unsigned int km2 = 0u;
        int cum = 0;
        #pragma unroll
        for (int k = 0; k < 32; k++) {
            unsigned int bit = (alive >> k) & 1u;
            bit &= (cum < need_n) ? 1u : 0u;    // cap: dropped rows don't suppress
            cum += (int)bit;
            km2 |= bit << k;
            alive &= ~((0u - bit) & tri[k]);
        }

        // E: record kept indices (threads 0..31)
        if (tid < 32 && ((km2 >> tid) & 1u))
            oi[cnt + __popc(km2 & ((1u << tid) - 1u))] = g * 32 + tid;
        cnt += cum;

        // F: OR kept rows' word-tid into owned state (conflict-free LDS reads)
        if (tid < ROWW) {
            unsigned int acc = 0u;
            #pragma unroll
            for (int k = 0; k < 32; k++)
                acc |= rows[cur][k * ROWW + tid] & (0u - ((km2 >> k) & 1u));
            st_word |= acc;
        }

        // G: publish next group's decision word (its owner thread)
        if (have_next && tid == g + 1) sw_lds[(g + 1) & 1] = st_word;

        // H: commit staged regs to the other buffer
        if (have_next) {
            uint4* dst = (uint4*)rows[cur ^ 1];
            #pragma unroll
            for (int i = 0; i < 6; i++) {
                int q = tid + i * 256;
                if (q < GQUADS) dst[q] = sreg[i];
            }
        }
        __syncthreads();
    }
    if (tid == 0) out_cnt[b] = cnt;
}

// ---------------- Kernel 6: compact + clip output ----------------
__global__ __launch_bounds__(256) void k_out(
    const float4* __restrict__ sboxes, const float* __restrict__ sscores,
    const int* __restrict__ out_idx, const int* __restrict__ out_cnt,
    float* __restrict__ out)
{
    int t = blockIdx.x * 256 + threadIdx.x;
    if (t >= BATCH * POST) return;
    int b = t / POST;
    int r = t - b * POST;
    float4 v = make_float4(0, 0, 0, 0);
    float sc = 0.f;
    if (r < out_cnt[b]) {
        int i = out_idx[b * POST + r];
        float4 bx = sboxes[(size_t)b * PRE + i];
        v.x = fminf(fmaxf(bx.x, 0.f), 1.f);
        v.y = fminf(fmaxf(bx.y, 0.f), 1.f);
        v.z = fminf(fmaxf(bx.z, 0.f), 1.f);
        v.w = fminf(fmaxf(bx.w, 0.f), 1.f);
        sc = sscores[(size_t)b * PRE + i];
    }
    ((float4*)out)[t] = v;                  // roi_bboxes
    out[(size_t)BATCH * POST * 4 + t] = sc; // roi_scores
}

// ---------------- host ----------------
extern "C" void kernel_launch(void* const* d_in, const int* in_sizes, int n_in,
                              void* d_out, int out_size, void* d_ws, size_t ws_size,
                              hipStream_t stream)
{
    const float* deltas  = (const float*)d_in[0];
    const float* probs   = (const float*)d_in[1];
    const float* anchors = (const float*)d_in[2];
    float* out = (float*)d_out;

    char* ws = (char*)d_ws;
    size_t off = 0;
    auto alloc = [&](size_t bytes) {
        size_t o = off;
        off = (off + bytes + 255) & ~(size_t)255;
        return o;
    };
    float4* boxes            = (float4*)(ws + alloc((size_t)BATCH * N_ANC * 16));
    unsigned long long* keys = (unsigned long long*)(ws + alloc((size_t)BATCH * SORT_N * 8));
    float4* sboxes           = (float4*)(ws + alloc((size_t)BATCH * PRE * 16));
    float* sscores           = (float*)(ws + alloc((size_t)BATCH * PRE * 4));
    unsigned int* mask       = (unsigned int*)(ws + alloc((size_t)BATCH * MROWS * ROWW * 4));
    int* oidx                = (int*)(ws + alloc((size_t)BATCH * POST * 4));
    int* ocnt                = (int*)(ws + alloc((size_t)BATCH * 4));

    k_decode<<<(BATCH * SORT_N + 255) / 256, 256, 0, stream>>>(deltas, probs, anchors, boxes, keys);
    k_sort_chunk<<<BATCH * 2, 1024, 0, stream>>>(keys);
    k_sort_merge<<<BATCH, 1024, 0, stream>>>(keys);
    k_gather<<<(BATCH * PRE + 255) / 256, 256, 0, stream>>>(keys, boxes, probs, sboxes, sscores);
    k_iou<<<dim3(24, 24, BATCH), 256, 0, stream>>>(sboxes, mask);
    k_scan<<<BATCH, 256, 0, stream>>>(mask, oidx, ocnt);
    k_out<<<(BATCH * POST + 255) / 256, 256, 0, stream>>>(sboxes, sscores, oidx, ocnt, out);
}